// Round 18
// baseline (294.468 us; speedup 1.0000x reference)
//
#include <hip/hip_runtime.h>
#include <hip/hip_fp16.h>

#define FH 128
#define NEG_SLOPE 0.2f
#define GBM 64
#define GBK 64
#define HT 1024        // CSR-build threads/block
#define TB 8           // edges per thread (batch)
#define NWMAX 12512    // LDS words: supports N <= 50048 packed-u8 bins
#define XLS 515        // xpack LDS row stride (515 mod 32 = 3 -> 2-way banks)

// Permuted H16 column layout: position p <-> feature f:
//   p = (f & 15) * 8 + (f >> 4),   f = (p & 7) * 16 + (p >> 3)
// Packed A16 layout (GEMM A operand): tile mg (16 rows), octet q (8 k-positions):
//   A16[((mg*nq + q)*16 + r)*8 + j]  => lane reads 16B coalesced per MFMA frag.

typedef _Float16 f16x8 __attribute__((ext_vector_type(8)));
typedef float f32x4 __attribute__((ext_vector_type(4)));

// ---------------- CSR pass A: per-block privatized histogram (NO global atomics)
__global__ __launch_bounds__(HT) void hist_kernel(const int* __restrict__ ei,
                                                  unsigned short* __restrict__ hist,
                                                  int E, int N) {
  __shared__ unsigned int lh[NWMAX];
  const int b = blockIdx.x, tid = threadIdx.x;
  const int nw = (N + 3) >> 2;
  for (int j = tid; j < nw; j += HT) lh[j] = 0u;
  __syncthreads();
  const int i0 = b * (HT * TB) + tid * TB;
  if (i0 + TB <= E) {
    int4 da = *(const int4*)&ei[E + i0];
    int4 db = *(const int4*)&ei[E + i0 + 4];
    int dv[8] = {da.x, da.y, da.z, da.w, db.x, db.y, db.z, db.w};
    #pragma unroll
    for (int k = 0; k < 8; k++)
      atomicAdd(&lh[dv[k] >> 2], 1u << ((dv[k] & 3) * 8));
  } else {
    for (int i = i0; i < E; i++) {
      int d = ei[E + i];
      atomicAdd(&lh[d >> 2], 1u << ((d & 3) * 8));
    }
  }
  __syncthreads();
  unsigned short* hb = hist + (size_t)b * N;
  for (int j = tid; j < nw; j += HT) {
    unsigned v = lh[j];
    int bin = j * 4;
    if (bin + 3 < N) {
      ushort4 o;
      o.x = v & 255u; o.y = (v >> 8) & 255u; o.z = (v >> 16) & 255u; o.w = v >> 24;
      *(ushort4*)&hb[bin] = o;
    } else {
      for (int k = 0; k < 4 && bin + k < N; k++) hb[bin + k] = (v >> (k * 8)) & 255u;
    }
  }
}

// ---------------- CSR pass B: column scan, IN-PLACE, 8 loads in flight ----------
__global__ void colscan_kernel(unsigned short* __restrict__ hist,
                               int* __restrict__ cnt, int N, int NBr) {
  int bin = blockIdx.x * 256 + threadIdx.x;
  if (bin >= N) return;
  int s = 0, b = 0;
  for (; b + 8 <= NBr; b += 8) {
    int t[8];
    #pragma unroll
    for (int k = 0; k < 8; k++) t[k] = hist[(size_t)(b + k) * N + bin];
    #pragma unroll
    for (int k = 0; k < 8; k++) {
      hist[(size_t)(b + k) * N + bin] = (unsigned short)s;   // becomes off[b][bin]
      s += t[k];
    }
  }
  for (; b < NBr; b++) {
    int t = hist[(size_t)b * N + bin];
    hist[(size_t)b * N + bin] = (unsigned short)s;
    s += t;
  }
  cnt[bin] = s;
}

// ---------------- 3-kernel exclusive scan of cnt -> rowptr ----------------------
__global__ void scan_blocksum(const int* __restrict__ deg, int* __restrict__ bsum, int n) {
  __shared__ int sm[256];
  int i = blockIdx.x * 256 + threadIdx.x;
  sm[threadIdx.x] = (i < n) ? deg[i] : 0;
  __syncthreads();
  for (int off = 128; off > 0; off >>= 1) {
    if (threadIdx.x < off) sm[threadIdx.x] += sm[threadIdx.x + off];
    __syncthreads();
  }
  if (threadIdx.x == 0) bsum[blockIdx.x] = sm[0];
}

__global__ void scan_bsum(int* __restrict__ bsum, int nb, int* __restrict__ rowptr, int N) {
  __shared__ int sm[1024];
  int t = threadIdx.x;
  int v = (t < nb) ? bsum[t] : 0;
  sm[t] = v;
  __syncthreads();
  for (int off = 1; off < 1024; off <<= 1) {
    int u = (t >= off) ? sm[t - off] : 0;
    __syncthreads();
    sm[t] += u;
    __syncthreads();
  }
  if (t < nb) bsum[t] = sm[t] - v;   // exclusive block offsets
  if (t == 1023) rowptr[N] = sm[1023];
}

__global__ void scan_final(const int* __restrict__ deg, const int* __restrict__ bsum,
                           int* __restrict__ rowptr, int n) {
  __shared__ int sm[256];
  int i = blockIdx.x * 256 + threadIdx.x;
  int v = (i < n) ? deg[i] : 0;
  sm[threadIdx.x] = v;
  __syncthreads();
  for (int off = 1; off < 256; off <<= 1) {
    int u = (threadIdx.x >= off) ? sm[threadIdx.x - off] : 0;
    __syncthreads();
    sm[threadIdx.x] += u;
    __syncthreads();
  }
  if (i < n) rowptr[i] = bsum[blockIdx.x] + sm[threadIdx.x] - v;
}

// ---------------- CSR pass C: placement via LDS cursors, 8 edges/thread ---------
// Scatter writes are non-temporal (skip L2 write-allocate on 4B random stores).
__global__ __launch_bounds__(HT) void place_kernel(const int* __restrict__ ei,
                                                   const float* __restrict__ ea,
                                                   const int* __restrict__ rowptr,
                                                   const unsigned short* __restrict__ off,
                                                   unsigned int* __restrict__ pack,
                                                   int E, int N) {
  __shared__ unsigned int lc[NWMAX];
  const int b = blockIdx.x, tid = threadIdx.x;
  const int nw = (N + 3) >> 2;
  for (int j = tid; j < nw; j += HT) lc[j] = 0u;
  __syncthreads();
  const unsigned short* __restrict__ ob = off + (size_t)b * N;
  const int i0 = b * (HT * TB) + tid * TB;
  if (i0 + TB <= E) {
    int4 sa = *(const int4*)&ei[i0];
    int4 sb = *(const int4*)&ei[i0 + 4];
    int4 da = *(const int4*)&ei[E + i0];
    int4 db = *(const int4*)&ei[E + i0 + 4];
    float4 aa = *(const float4*)&ea[i0];
    float4 ab = *(const float4*)&ea[i0 + 4];
    int sv[8] = {sa.x, sa.y, sa.z, sa.w, sb.x, sb.y, sb.z, sb.w};
    int dv[8] = {da.x, da.y, da.z, da.w, db.x, db.y, db.z, db.w};
    float av[8] = {aa.x, aa.y, aa.z, aa.w, ab.x, ab.y, ab.z, ab.w};
    unsigned rr[8];
    #pragma unroll
    for (int k = 0; k < 8; k++)
      rr[k] = atomicAdd(&lc[dv[k] >> 2], 1u << ((dv[k] & 3) * 8));
    int pos[8];
    #pragma unroll
    for (int k = 0; k < 8; k++)
      pos[k] = rowptr[dv[k]] + (int)ob[dv[k]] + (int)((rr[k] >> ((dv[k] & 3) * 8)) & 255u);
    #pragma unroll
    for (int k = 0; k < 8; k++)
      __builtin_nontemporal_store(
        ((unsigned)sv[k] << 16) | __half_as_ushort(__float2half(av[k])), &pack[pos[k]]);
  } else {
    for (int i = i0; i < E; i++) {
      int d = ei[E + i];
      unsigned r = atomicAdd(&lc[d >> 2], 1u << ((d & 3) * 8));
      int local = (r >> ((d & 3) * 8)) & 255;
      int pos = rowptr[d] + (int)ob[d] + local;
      __builtin_nontemporal_store(
        ((unsigned)ei[i] << 16) | __half_as_ushort(__float2half(ea[i])), &pack[pos]);
    }
  }
}

// ---------------- c = We . ae (scalar per layer) --------------------------------
__global__ void cvec_kernel(const float* __restrict__ We1, const float* __restrict__ ae1,
                            const float* __restrict__ We2, const float* __restrict__ ae2,
                            float* __restrict__ cv) {
  int l = threadIdx.x;  // 64 lanes
  float s1 = We1[l] * ae1[l] + We1[l + 64] * ae1[l + 64];
  float s2 = We2[l] * ae2[l] + We2[l + 64] * ae2[l + 64];
  for (int off = 32; off; off >>= 1) { s1 += __shfl_down(s1, off); s2 += __shfl_down(s2, off); }
  if (l == 0) { cv[0] = s1; cv[1] = s2; }
}

// ---------------- both W conversions in ONE launch ------------------------------
// W1t: [128][K1p] natural-k.  W2t: [128][128] permuted-k (packed-A positions).
__global__ void wcvt_kernel(const float* __restrict__ W1, __half* __restrict__ W1t,
                            int K1, int K1p,
                            const float* __restrict__ W2, __half* __restrict__ W2t) {
  int idx = blockIdx.x * 256 + threadIdx.x;
  int n1 = 128 * K1p;
  if (idx < n1) {
    int n = idx / K1p, k = idx - n * K1p;
    W1t[idx] = (k < K1) ? __float2half(W1[(size_t)k * 128 + n]) : __float2half(0.f);
  } else {
    int j = idx - n1;
    if (j < 128 * 128) {
      int n = j >> 7, p = j & 127;
      int k = (p & 7) * 16 + (p >> 3);   // feature index for packed position p
      W2t[j] = __float2half(W2[(size_t)k * 128 + n]);
    }
  }
}

// ---------------- xpack: X f32 [M][K] -> packed fp16 A16 tiles (R15, measured) --
__global__ __launch_bounds__(256) void xpack_kernel(const float* __restrict__ X,
                                                    __half* __restrict__ A16,
                                                    int K, int Kpad) {
  __shared__ float Ls[16 * XLS];
  const int mg = blockIdx.x, tid = threadIdx.x;
  const int nq = Kpad >> 3;
  const int total = 16 * K;
  const float* __restrict__ Xb = X + (size_t)mg * total;
  for (int i = tid; i < total; i += 256) {
    int row = i / K;
    Ls[row * XLS + (i - row * K)] = Xb[i];
  }
  {
    int npad = 16 * (Kpad - K);
    for (int i = tid; i < npad; i += 256) {
      int row = i / (Kpad - K);
      Ls[row * XLS + K + (i - row * (Kpad - K))] = 0.f;
    }
  }
  __syncthreads();
  _Float16* dst = (_Float16*)A16 + (size_t)mg * nq * 128;
  const int nfr = nq * 16;
  for (int c = tid; c < nfr; c += 256) {
    int q = c >> 4, r = c & 15;
    const float* src = &Ls[r * XLS + q * 8];
    f16x8 v;
    #pragma unroll
    for (int j = 0; j < 8; j++) v[j] = (_Float16)src[j];
    *(f16x8*)&dst[(size_t)c * 8] = v;
  }
}

// ---------------- MFMA fp16 GEMM: packed-A16 input, R10 B-staging (measured) ----
__global__ __launch_bounds__(256, 4) void mfma_gemm_kernel(
    const __half* __restrict__ A16_, const __half* __restrict__ Wt_,
    const float* __restrict__ avs, const float* __restrict__ avd,
    __half* __restrict__ H16, float* __restrict__ a_s, float* __restrict__ a_d,
    int M, int Kpad) {
  __shared__ _Float16 Bl[2 * 8 * 64 * 8];   // [kt][nt][frag-lane][j] = 16 KB
  const _Float16* __restrict__ A16 = (const _Float16*)A16_;
  const _Float16* __restrict__ Wt  = (const _Float16*)Wt_;
  const int tid  = threadIdx.x;
  const int lane = tid & 63;
  const int w    = tid >> 6;
  const int m0   = blockIdx.x * GBM;
  const int nq   = Kpad >> 3;

  f32x4 acc[8];
  #pragma unroll
  for (int i = 0; i < 8; i++) acc[i] = (f32x4){0.f, 0.f, 0.f, 0.f};

  const int mgc = min(m0 / 16 + w, M / 16 - 1);   // M%16==0
  const _Float16* __restrict__ Abase =
      A16 + (size_t)mgc * nq * 128 + (lane >> 4) * 128 + (lane & 15) * 8;

  const int sg = tid & 7, snb = tid >> 3;    // B staging coords (R10 pattern)

  for (int k0 = 0; k0 < Kpad; k0 += GBK) {
    #pragma unroll
    for (int i = 0; i < 4; i++) {
      int n = snb + 32 * i;
      f16x8 v = *(const f16x8*)(Wt + (size_t)n * Kpad + k0 + sg * 8);
      int kt = sg >> 2, nt = n >> 4;
      int fl = (n & 15) + (sg & 3) * 16;
      *(f16x8*)&Bl[((kt * 8 + nt) * 64 + fl) * 8] = v;
    }
    __syncthreads();
    #pragma unroll
    for (int kt = 0; kt < 2; kt++) {
      f16x8 af = *(const f16x8*)(Abase + (size_t)k0 * 16 + kt * 512);  // 16B coalesced
      #pragma unroll
      for (int nt = 0; nt < 8; nt++) {
        f16x8 bf = *(const f16x8*)&Bl[((kt * 8 + nt) * 64 + lane) * 8];
        acc[nt] = __builtin_amdgcn_mfma_f32_16x16x32_f16(af, bf, acc[nt], 0, 0, 0);
      }
    }
    __syncthreads();
  }

  // ---- epilogue: permuted coalesced fp16 store + fused a_s/a_d (f32) -----------
  const int rbase = m0 + w * 16 + (lane >> 4) * 4;
  const int col   = lane & 15;
  float as_v[8], ad_v[8];
  #pragma unroll
  for (int nt = 0; nt < 8; nt++) {
    as_v[nt] = avs[nt * 16 + col];      // natural feature indexing
    ad_v[nt] = avd[nt * 16 + col];
  }
  #pragma unroll
  for (int r = 0; r < 4; r++) {
    int gm = rbase + r;
    float ps = 0.f, pd = 0.f;
    #pragma unroll
    for (int nt = 0; nt < 8; nt++) {
      ps += acc[nt][r] * as_v[nt];
      pd += acc[nt][r] * ad_v[nt];
    }
    #pragma unroll
    for (int msk = 1; msk < 16; msk <<= 1) {
      ps += __shfl_xor(ps, msk);
      pd += __shfl_xor(pd, msk);
    }
    if (gm < M) {
      __half2 h0 = __floats2half2_rn(acc[0][r], acc[1][r]);
      __half2 h1 = __floats2half2_rn(acc[2][r], acc[3][r]);
      __half2 h2 = __floats2half2_rn(acc[4][r], acc[5][r]);
      __half2 h3 = __floats2half2_rn(acc[6][r], acc[7][r]);
      uint4 u;
      u.x = *(unsigned*)&h0; u.y = *(unsigned*)&h1;
      u.z = *(unsigned*)&h2; u.w = *(unsigned*)&h3;
      *(uint4*)&H16[(size_t)gm * FH + col * 8] = u;
      if (col == 0) { a_s[gm] = ps; a_d[gm] = pd; }
    }
  }
}

// ---------------- GAT aggregation: wave/node, 4 slots x 16 lanes, unroll x4 -----
// OUTP=1: write packed-A16 fp16 (feeds next GEMM).
// OUTP=0: fused node head — no feature output at all; writes bout + pbuf.
template<int OUTP>
__global__ __launch_bounds__(256) void agg_kernel(
    const __half* __restrict__ H16, const int* __restrict__ rowptr,
    const unsigned int* __restrict__ pack,
    const float* __restrict__ a_s, const float* __restrict__ a_d,
    const float* __restrict__ cv, int cidx,
    const float* __restrict__ bias,
    __half* __restrict__ HoutP,
    const float* __restrict__ Wb, const float* __restrict__ bb,
    const float* __restrict__ Ww, const float* __restrict__ mask,
    float* __restrict__ bout, float* __restrict__ pbuf, int N) {
  const int node = (blockIdx.x * 256 + threadIdx.x) >> 6;
  const int lane = threadIdx.x & 63;
  const int slot = lane >> 4, sl = lane & 15;
  if (node >= N) return;
  const _Float16* __restrict__ Hh = (const _Float16*)H16;
  const float c   = cv[cidx];
  const float adn = a_d[node];
  const int beg = rowptr[node], end = rowptr[node + 1];

  float acc[8] = {0.f, 0.f, 0.f, 0.f, 0.f, 0.f, 0.f, 0.f};
  float accB[8] = {0.f, 0.f, 0.f, 0.f, 0.f, 0.f, 0.f, 0.f};
  float den = 0.f, ea_tot = 0.f, denB = 0.f, eaB = 0.f;

  int p = beg + slot;
  for (; p + 12 < end; p += 16) {            // 4 edges per slot in flight
    unsigned w0 = pack[p],     w1 = pack[p + 4];
    unsigned w2 = pack[p + 8], w3 = pack[p + 12];
    int s0 = w0 >> 16, s1 = w1 >> 16, s2 = w2 >> 16, s3 = w3 >> 16;
    float e0 = __half2float(__ushort_as_half((unsigned short)(w0 & 0xffff)));
    float e1 = __half2float(__ushort_as_half((unsigned short)(w1 & 0xffff)));
    float e2 = __half2float(__ushort_as_half((unsigned short)(w2 & 0xffff)));
    float e3 = __half2float(__ushort_as_half((unsigned short)(w3 & 0xffff)));
    float as0 = a_s[s0], as1 = a_s[s1], as2 = a_s[s2], as3 = a_s[s3];
    f16x8 h0 = *(const f16x8*)(Hh + (size_t)s0 * FH + sl * 8);
    f16x8 h1 = *(const f16x8*)(Hh + (size_t)s1 * FH + sl * 8);
    f16x8 h2 = *(const f16x8*)(Hh + (size_t)s2 * FH + sl * 8);
    f16x8 h3 = *(const f16x8*)(Hh + (size_t)s3 * FH + sl * 8);
    float al0 = as0 + adn + c * e0;
    float al1 = as1 + adn + c * e1;
    float al2 = as2 + adn + c * e2;
    float al3 = as3 + adn + c * e3;
    al0 = fmaxf(al0, NEG_SLOPE * al0);
    al1 = fmaxf(al1, NEG_SLOPE * al1);
    al2 = fmaxf(al2, NEG_SLOPE * al2);
    al3 = fmaxf(al3, NEG_SLOPE * al3);
    float ex0 = __expf(al0), ex1 = __expf(al1);
    float ex2 = __expf(al2), ex3 = __expf(al3);
    ea_tot += e0 + e2; eaB += e1 + e3;
    den += ex0 + ex2; denB += ex1 + ex3;
    #pragma unroll
    for (int j = 0; j < 8; j++) {
      acc[j]  += ex0 * (float)h0[j] + ex2 * (float)h2[j];
      accB[j] += ex1 * (float)h1[j] + ex3 * (float)h3[j];
    }
  }
  for (; p < end; p += 4) {
    unsigned w0 = pack[p];
    int s0 = w0 >> 16;
    float e0 = __half2float(__ushort_as_half((unsigned short)(w0 & 0xffff)));
    float al = a_s[s0] + adn + c * e0;
    al = fmaxf(al, NEG_SLOPE * al);
    float ex = __expf(al);
    f16x8 h = *(const f16x8*)(Hh + (size_t)s0 * FH + sl * 8);
    ea_tot += e0;
    den += ex;
    #pragma unroll
    for (int j = 0; j < 8; j++) acc[j] += ex * (float)h[j];
  }
  den += denB; ea_tot += eaB;
  #pragma unroll
  for (int j = 0; j < 8; j++) acc[j] += accB[j];
  // cross-slot reduce (slots differ in lane bits 4,5)
  ea_tot += __shfl_xor(ea_tot, 16); ea_tot += __shfl_xor(ea_tot, 32);
  den    += __shfl_xor(den,    16); den    += __shfl_xor(den,    32);
  #pragma unroll
  for (int j = 0; j < 8; j++) {
    acc[j] += __shfl_xor(acc[j], 16);
    acc[j] += __shfl_xor(acc[j], 32);
  }
  { // self loop, ea = mean of incoming edge attrs (0 if none)
    int dg = end - beg;
    float eal = ea_tot / fmaxf((float)dg, 1.f);
    float al = a_s[node] + adn + c * eal;
    al = fmaxf(al, NEG_SLOPE * al);
    float ex = __expf(al);
    f16x8 h = *(const f16x8*)(Hh + (size_t)node * FH + sl * 8);
    den += ex;
    #pragma unroll
    for (int j = 0; j < 8; j++) acc[j] += ex * (float)h[j];
  }
  if (slot == 0) {
    float inv = 1.f / den;
    float v[8];
    #pragma unroll
    for (int j = 0; j < 8; j++)
      v[j] = fmaxf(acc[j] * inv + bias[j * 16 + sl], 0.f);   // permuted bias gather
    if (OUTP) {
      // packed-A16 write: tile mg=node>>4, octet q=sl, row r=node&15
      f16x8 o;
      #pragma unroll
      for (int j = 0; j < 8; j++) o[j] = (_Float16)v[j];
      int mg = node >> 4, r = node & 15;
      *(f16x8*)((_Float16*)HoutP + (((size_t)mg * 16 + sl) * 16 + r) * 8) = o;
    } else {
      // fused node head: sb = v . Wb, sw = v . Ww over this slot's 8 features
      float sb = 0.f, sw = 0.f;
      #pragma unroll
      for (int j = 0; j < 8; j++) {
        int f = j * 16 + sl;                 // feature of permuted position sl*8+j
        sb += v[j] * Wb[f];
        sw += v[j] * Ww[f];
      }
      #pragma unroll
      for (int m = 1; m < 16; m <<= 1) {     // reduce across slot-0's 16 lanes
        sb += __shfl_xor(sb, m);
        sw += __shfl_xor(sw, m);
      }
      if (sl == 0) {
        bout[node] = (sb + bb[0]) * mask[node];
        pbuf[node] = sw;
      }
    }
  }
}

// ---------------- edge head: w = 0.5*(p[src]+p[dst]) + bw, x4 vectorized ---------
__global__ void edge_head_kernel(const int* __restrict__ ei, const float* __restrict__ p,
                                 const float* __restrict__ bw, float* __restrict__ w, int E) {
  int base = (blockIdx.x * 256 + threadIdx.x) * 4;
  if (base >= E) return;
  float b = bw[0];
  if (base + 4 <= E) {
    int4 s = *(const int4*)&ei[base];
    int4 d = *(const int4*)&ei[E + base];
    float4 o;
    o.x = 0.5f * (p[s.x] + p[d.x]) + b;
    o.y = 0.5f * (p[s.y] + p[d.y]) + b;
    o.z = 0.5f * (p[s.z] + p[d.z]) + b;
    o.w = 0.5f * (p[s.w] + p[d.w]) + b;
    *(float4*)&w[base] = o;
  } else {
    for (int e = base; e < E; e++)
      w[e] = 0.5f * (p[ei[e]] + p[ei[E + e]]) + b;
  }
}

extern "C" void kernel_launch(void* const* d_in, const int* in_sizes, int n_in,
                              void* d_out, int out_size, void* d_ws, size_t ws_size,
                              hipStream_t stream) {
  (void)n_in; (void)out_size; (void)ws_size;
  const float* x    = (const float*)d_in[0];
  const int*   ei   = (const int*)  d_in[1];
  const float* ea   = (const float*)d_in[2];
  const float* mask = (const float*)d_in[3];
  const float* W1   = (const float*)d_in[4];
  const float* b1   = (const float*)d_in[5];
  const float* as1  = (const float*)d_in[6];
  const float* ad1  = (const float*)d_in[7];
  const float* We1  = (const float*)d_in[8];
  const float* ae1  = (const float*)d_in[9];
  const float* W2   = (const float*)d_in[10];
  const float* b2   = (const float*)d_in[11];
  const float* as2  = (const float*)d_in[12];
  const float* ad2  = (const float*)d_in[13];
  const float* We2  = (const float*)d_in[14];
  const float* ae2  = (const float*)d_in[15];
  const float* Wb   = (const float*)d_in[16];
  const float* bb   = (const float*)d_in[17];
  const float* Ww   = (const float*)d_in[18];
  const float* bw   = (const float*)d_in[19];

  const int N  = in_sizes[3];          // 50000 (divisible by 16)
  const int E  = in_sizes[1] / 2;      // 1600000
  const int K1 = in_sizes[0] / N;      // 503
  const int K1p = (K1 + GBK - 1) & ~(GBK - 1);   // 512
  const int NBr = (E + HT * TB - 1) / (HT * TB); // 196 CSR-build blocks
  const int NT  = N / 16;                        // 3125 row tiles

  // ---- workspace carve-up (256B aligned) ----
  char* ws = (char*)d_ws;
  size_t off0 = 0;
  auto alloc = [&](size_t bytes) -> char* {
    char* q = ws + off0;
    off0 = (off0 + bytes + 255) & ~(size_t)255;
    return q;
  };
  int*   cnt    = (int*)  alloc((size_t)N * 4);
  int*   rowptr = (int*)  alloc((size_t)(N + 1) * 4);
  int*   bsum   = (int*)  alloc(1024 * 4);
  // Union region: hist/off (19.6 MB, dies after place) -> XA16 (51.2 MB, dies
  // after gemm1) -> HB16 (12.8 MB, written by agg1 after gemm1, dies after gemm2)
  size_t uszA = (size_t)NBr * N * 2;
  size_t uszB = (size_t)NT * (K1p / 8) * 256;    // 51.2 MB
  char*  uni  = alloc(uszA > uszB ? uszA : uszB);
  unsigned short* hist = (unsigned short*)uni;
  __half* XA16 = (__half*)uni;
  __half* HB16 = (__half*)uni;
  unsigned int* pack = (unsigned int*)alloc((size_t)E * 4);
  float* a_s    = (float*)alloc((size_t)N * 4);
  float* a_d    = (float*)alloc((size_t)N * 4);
  __half* H16   = (__half*)alloc((size_t)N * FH * 2);  // fp16 GEMM out (permuted cols)
  float* pbuf   = (float*)alloc((size_t)N * 4);
  float* cv     = (float*)alloc(8);
  __half* W1t   = (__half*)alloc((size_t)FH * K1p * 2);
  __half* W2t   = (__half*)alloc((size_t)FH * FH * 2);

  float* w_out = (float*)d_out;        // [E]
  float* b_out = (float*)d_out + E;    // [N]

  const int nb  = (N + 255) / 256;
  const int gb  = (N + GBM - 1) / GBM;
  const int ab  = (N + 3) / 4;                    // agg: 4 nodes/block
  const int eb4 = (E + 1023) / 1024;              // edge head: 4 edges/thread
  const int wcb = (128 * K1p + 128 * 128 + 255) / 256;

  // topology precompute: ZERO global atomics, 8 edges/thread batched MLP
  hist_kernel   <<<NBr, HT, 0, stream>>>(ei, hist, E, N);
  colscan_kernel<<<nb, 256, 0, stream>>>(hist, cnt, N, NBr);
  scan_blocksum <<<nb, 256, 0, stream>>>(cnt, bsum, N);
  scan_bsum     <<<1, 1024, 0, stream>>>(bsum, nb, rowptr, N);
  scan_final    <<<nb, 256, 0, stream>>>(cnt, bsum, rowptr, N);
  place_kernel  <<<NBr, HT, 0, stream>>>(ei, ea, rowptr, hist, pack, E, N);
  cvec_kernel   <<<1, 64, 0, stream>>>(We1, ae1, We2, ae2, cv);
  wcvt_kernel   <<<wcb, 256, 0, stream>>>(W1, W1t, K1, K1p, W2, W2t);
  // X -> packed fp16 fragment tiles (after place: reuses hist region)
  xpack_kernel  <<<NT, 256, 0, stream>>>(x, XA16, K1, K1p);

  // layer 1 (packed-A GEMM, fused a_s/a_d; H16 permuted); agg1 emits packed A16
  mfma_gemm_kernel<<<gb, 256, 0, stream>>>(XA16, W1t, as1, ad1, H16, a_s, a_d, N, K1p);
  agg_kernel<1><<<ab, 256, 0, stream>>>(H16, rowptr, pack, a_s, a_d, cv, 0, b1,
                                        HB16, nullptr, nullptr, nullptr, nullptr,
                                        nullptr, nullptr, N);
  // layer 2 (packed-A input from agg1; W2t k-permuted to match positions)
  mfma_gemm_kernel<<<gb, 256, 0, stream>>>(HB16, W2t, as2, ad2, H16, a_s, a_d, N, FH);
  // agg2 with fused node head: writes b_out and pbuf directly, no feature output
  agg_kernel<0><<<ab, 256, 0, stream>>>(H16, rowptr, pack, a_s, a_d, cv, 1, b2,
                                        nullptr, Wb, bb, Ww, mask, b_out, pbuf, N);
  edge_head_kernel<<<eb4, 256, 0, stream>>>(ei, pbuf, bw, w_out, E);
}

// Round 19
// 267.758 us; speedup vs baseline: 1.0998x; 1.0998x over previous
//
#include <hip/hip_runtime.h>
#include <hip/hip_fp16.h>

#define FH 128
#define NEG_SLOPE 0.2f
#define GBM 64
#define GBK 64
#define HT 1024        // CSR-build threads/block
#define TB 8           // edges per thread (batch)
#define NWMAX 12512    // LDS words: supports N <= 50048 packed-u8 bins
#define XLS 515        // xpack LDS row stride (515 mod 32 = 3 -> 2-way banks)

// Permuted H16 column layout: position p <-> feature f:
//   p = (f & 15) * 8 + (f >> 4),   f = (p & 7) * 16 + (p >> 3)
// Packed A16 layout (GEMM A operand): tile mg (16 rows), octet q (8 k-positions):
//   A16[((mg*nq + q)*16 + r)*8 + j]  => lane reads 16B coalesced per MFMA frag.

typedef _Float16 f16x8 __attribute__((ext_vector_type(8)));
typedef float f32x4 __attribute__((ext_vector_type(4)));

// ---------------- CSR pass A: per-block privatized histogram (NO global atomics)
__global__ __launch_bounds__(HT) void hist_kernel(const int* __restrict__ ei,
                                                  unsigned short* __restrict__ hist,
                                                  int E, int N) {
  __shared__ unsigned int lh[NWMAX];
  const int b = blockIdx.x, tid = threadIdx.x;
  const int nw = (N + 3) >> 2;
  for (int j = tid; j < nw; j += HT) lh[j] = 0u;
  __syncthreads();
  const int i0 = b * (HT * TB) + tid * TB;
  if (i0 + TB <= E) {
    int4 da = *(const int4*)&ei[E + i0];
    int4 db = *(const int4*)&ei[E + i0 + 4];
    int dv[8] = {da.x, da.y, da.z, da.w, db.x, db.y, db.z, db.w};
    #pragma unroll
    for (int k = 0; k < 8; k++)
      atomicAdd(&lh[dv[k] >> 2], 1u << ((dv[k] & 3) * 8));
  } else {
    for (int i = i0; i < E; i++) {
      int d = ei[E + i];
      atomicAdd(&lh[d >> 2], 1u << ((d & 3) * 8));
    }
  }
  __syncthreads();
  unsigned short* hb = hist + (size_t)b * N;
  for (int j = tid; j < nw; j += HT) {
    unsigned v = lh[j];
    int bin = j * 4;
    if (bin + 3 < N) {
      ushort4 o;
      o.x = v & 255u; o.y = (v >> 8) & 255u; o.z = (v >> 16) & 255u; o.w = v >> 24;
      *(ushort4*)&hb[bin] = o;
    } else {
      for (int k = 0; k < 4 && bin + k < N; k++) hb[bin + k] = (v >> (k * 8)) & 255u;
    }
  }
}

// ---------------- CSR pass B: column scan, IN-PLACE, 8 loads in flight ----------
__global__ void colscan_kernel(unsigned short* __restrict__ hist,
                               int* __restrict__ cnt, int N, int NBr) {
  int bin = blockIdx.x * 256 + threadIdx.x;
  if (bin >= N) return;
  int s = 0, b = 0;
  for (; b + 8 <= NBr; b += 8) {
    int t[8];
    #pragma unroll
    for (int k = 0; k < 8; k++) t[k] = hist[(size_t)(b + k) * N + bin];
    #pragma unroll
    for (int k = 0; k < 8; k++) {
      hist[(size_t)(b + k) * N + bin] = (unsigned short)s;   // becomes off[b][bin]
      s += t[k];
    }
  }
  for (; b < NBr; b++) {
    int t = hist[(size_t)b * N + bin];
    hist[(size_t)b * N + bin] = (unsigned short)s;
    s += t;
  }
  cnt[bin] = s;
}

// ---------------- 3-kernel exclusive scan of cnt -> rowptr ----------------------
__global__ void scan_blocksum(const int* __restrict__ deg, int* __restrict__ bsum, int n) {
  __shared__ int sm[256];
  int i = blockIdx.x * 256 + threadIdx.x;
  sm[threadIdx.x] = (i < n) ? deg[i] : 0;
  __syncthreads();
  for (int off = 128; off > 0; off >>= 1) {
    if (threadIdx.x < off) sm[threadIdx.x] += sm[threadIdx.x + off];
    __syncthreads();
  }
  if (threadIdx.x == 0) bsum[blockIdx.x] = sm[0];
}

__global__ void scan_bsum(int* __restrict__ bsum, int nb, int* __restrict__ rowptr, int N) {
  __shared__ int sm[1024];
  int t = threadIdx.x;
  int v = (t < nb) ? bsum[t] : 0;
  sm[t] = v;
  __syncthreads();
  for (int off = 1; off < 1024; off <<= 1) {
    int u = (t >= off) ? sm[t - off] : 0;
    __syncthreads();
    sm[t] += u;
    __syncthreads();
  }
  if (t < nb) bsum[t] = sm[t] - v;   // exclusive block offsets
  if (t == 1023) rowptr[N] = sm[1023];
}

__global__ void scan_final(const int* __restrict__ deg, const int* __restrict__ bsum,
                           int* __restrict__ rowptr, int n) {
  __shared__ int sm[256];
  int i = blockIdx.x * 256 + threadIdx.x;
  int v = (i < n) ? deg[i] : 0;
  sm[threadIdx.x] = v;
  __syncthreads();
  for (int off = 1; off < 256; off <<= 1) {
    int u = (threadIdx.x >= off) ? sm[threadIdx.x - off] : 0;
    __syncthreads();
    sm[threadIdx.x] += u;
    __syncthreads();
  }
  if (i < n) rowptr[i] = bsum[blockIdx.x] + sm[threadIdx.x] - v;
}

// ---------------- CSR pass C: placement via LDS cursors, 8 edges/thread ---------
__global__ __launch_bounds__(HT) void place_kernel(const int* __restrict__ ei,
                                                   const float* __restrict__ ea,
                                                   const int* __restrict__ rowptr,
                                                   const unsigned short* __restrict__ off,
                                                   unsigned int* __restrict__ pack,
                                                   int E, int N) {
  __shared__ unsigned int lc[NWMAX];
  const int b = blockIdx.x, tid = threadIdx.x;
  const int nw = (N + 3) >> 2;
  for (int j = tid; j < nw; j += HT) lc[j] = 0u;
  __syncthreads();
  const unsigned short* __restrict__ ob = off + (size_t)b * N;
  const int i0 = b * (HT * TB) + tid * TB;
  if (i0 + TB <= E) {
    int4 sa = *(const int4*)&ei[i0];
    int4 sb = *(const int4*)&ei[i0 + 4];
    int4 da = *(const int4*)&ei[E + i0];
    int4 db = *(const int4*)&ei[E + i0 + 4];
    float4 aa = *(const float4*)&ea[i0];
    float4 ab = *(const float4*)&ea[i0 + 4];
    int sv[8] = {sa.x, sa.y, sa.z, sa.w, sb.x, sb.y, sb.z, sb.w};
    int dv[8] = {da.x, da.y, da.z, da.w, db.x, db.y, db.z, db.w};
    float av[8] = {aa.x, aa.y, aa.z, aa.w, ab.x, ab.y, ab.z, ab.w};
    unsigned rr[8];
    #pragma unroll
    for (int k = 0; k < 8; k++)
      rr[k] = atomicAdd(&lc[dv[k] >> 2], 1u << ((dv[k] & 3) * 8));
    int pos[8];
    #pragma unroll
    for (int k = 0; k < 8; k++)
      pos[k] = rowptr[dv[k]] + (int)ob[dv[k]] + (int)((rr[k] >> ((dv[k] & 3) * 8)) & 255u);
    #pragma unroll
    for (int k = 0; k < 8; k++)
      pack[pos[k]] = ((unsigned)sv[k] << 16) | __half_as_ushort(__float2half(av[k]));
  } else {
    for (int i = i0; i < E; i++) {
      int d = ei[E + i];
      unsigned r = atomicAdd(&lc[d >> 2], 1u << ((d & 3) * 8));
      int local = (r >> ((d & 3) * 8)) & 255;
      int pos = rowptr[d] + (int)ob[d] + local;
      pack[pos] = ((unsigned)ei[i] << 16) | __half_as_ushort(__float2half(ea[i]));
    }
  }
}

// ---------------- c = We . ae (scalar per layer) --------------------------------
__global__ void cvec_kernel(const float* __restrict__ We1, const float* __restrict__ ae1,
                            const float* __restrict__ We2, const float* __restrict__ ae2,
                            float* __restrict__ cv) {
  int l = threadIdx.x;  // 64 lanes
  float s1 = We1[l] * ae1[l] + We1[l + 64] * ae1[l + 64];
  float s2 = We2[l] * ae2[l] + We2[l + 64] * ae2[l + 64];
  for (int off = 32; off; off >>= 1) { s1 += __shfl_down(s1, off); s2 += __shfl_down(s2, off); }
  if (l == 0) { cv[0] = s1; cv[1] = s2; }
}

// ---------------- W (K x 128) -> Wt fp16 [128][Kpad]; perm=1 permutes k ----------
__global__ void wcvt_kernel(const float* __restrict__ W, __half* __restrict__ Wt,
                            int K, int Kpad, int perm) {
  int idx = blockIdx.x * 256 + threadIdx.x;
  if (idx >= 128 * Kpad) return;
  int n = idx / Kpad, p = idx - n * Kpad;
  int k = perm ? ((p & 7) * 16 + (p >> 3)) : p;   // feature index for slot p
  Wt[idx] = (k < K) ? __float2half(W[(size_t)k * 128 + n]) : __float2half(0.f);
}

// ---------------- xpack: X f32 [M][K] -> packed fp16 A16 tiles (R15, measured) --
__global__ __launch_bounds__(256) void xpack_kernel(const float* __restrict__ X,
                                                    __half* __restrict__ A16,
                                                    int K, int Kpad) {
  __shared__ float Ls[16 * XLS];
  const int mg = blockIdx.x, tid = threadIdx.x;
  const int nq = Kpad >> 3;
  const int total = 16 * K;
  const float* __restrict__ Xb = X + (size_t)mg * total;
  for (int i = tid; i < total; i += 256) {
    int row = i / K;
    Ls[row * XLS + (i - row * K)] = Xb[i];
  }
  {
    int npad = 16 * (Kpad - K);
    for (int i = tid; i < npad; i += 256) {
      int row = i / (Kpad - K);
      Ls[row * XLS + K + (i - row * (Kpad - K))] = 0.f;
    }
  }
  __syncthreads();
  _Float16* dst = (_Float16*)A16 + (size_t)mg * nq * 128;
  const int nfr = nq * 16;
  for (int c = tid; c < nfr; c += 256) {
    int q = c >> 4, r = c & 15;
    const float* src = &Ls[r * XLS + q * 8];
    f16x8 v;
    #pragma unroll
    for (int j = 0; j < 8; j++) v[j] = (_Float16)src[j];
    *(f16x8*)&dst[(size_t)c * 8] = v;
  }
}

// ---------------- MFMA fp16 GEMM: packed-A16 input, R10 B-staging (measured) ----
__global__ __launch_bounds__(256, 4) void mfma_gemm_kernel(
    const __half* __restrict__ A16_, const __half* __restrict__ Wt_,
    const float* __restrict__ avs, const float* __restrict__ avd,
    __half* __restrict__ H16, float* __restrict__ a_s, float* __restrict__ a_d,
    int M, int Kpad) {
  __shared__ _Float16 Bl[2 * 8 * 64 * 8];   // [kt][nt][frag-lane][j] = 16 KB
  const _Float16* __restrict__ A16 = (const _Float16*)A16_;
  const _Float16* __restrict__ Wt  = (const _Float16*)Wt_;
  const int tid  = threadIdx.x;
  const int lane = tid & 63;
  const int w    = tid >> 6;
  const int m0   = blockIdx.x * GBM;
  const int nq   = Kpad >> 3;

  f32x4 acc[8];
  #pragma unroll
  for (int i = 0; i < 8; i++) acc[i] = (f32x4){0.f, 0.f, 0.f, 0.f};

  const int mgc = min(m0 / 16 + w, M / 16 - 1);   // M%16==0
  const _Float16* __restrict__ Abase =
      A16 + (size_t)mgc * nq * 128 + (lane >> 4) * 128 + (lane & 15) * 8;

  const int sg = tid & 7, snb = tid >> 3;    // B staging coords (R10 pattern)

  for (int k0 = 0; k0 < Kpad; k0 += GBK) {
    #pragma unroll
    for (int i = 0; i < 4; i++) {
      int n = snb + 32 * i;
      f16x8 v = *(const f16x8*)(Wt + (size_t)n * Kpad + k0 + sg * 8);
      int kt = sg >> 2, nt = n >> 4;
      int fl = (n & 15) + (sg & 3) * 16;
      *(f16x8*)&Bl[((kt * 8 + nt) * 64 + fl) * 8] = v;
    }
    __syncthreads();
    #pragma unroll
    for (int kt = 0; kt < 2; kt++) {
      f16x8 af = *(const f16x8*)(Abase + (size_t)k0 * 16 + kt * 512);  // 16B coalesced
      #pragma unroll
      for (int nt = 0; nt < 8; nt++) {
        f16x8 bf = *(const f16x8*)&Bl[((kt * 8 + nt) * 64 + lane) * 8];
        acc[nt] = __builtin_amdgcn_mfma_f32_16x16x32_f16(af, bf, acc[nt], 0, 0, 0);
      }
    }
    __syncthreads();
  }

  // ---- epilogue: permuted coalesced fp16 store + fused a_s/a_d (f32) -----------
  const int rbase = m0 + w * 16 + (lane >> 4) * 4;
  const int col   = lane & 15;
  float as_v[8], ad_v[8];
  #pragma unroll
  for (int nt = 0; nt < 8; nt++) {
    as_v[nt] = avs[nt * 16 + col];      // natural feature indexing
    ad_v[nt] = avd[nt * 16 + col];
  }
  #pragma unroll
  for (int r = 0; r < 4; r++) {
    int gm = rbase + r;
    float ps = 0.f, pd = 0.f;
    #pragma unroll
    for (int nt = 0; nt < 8; nt++) {
      ps += acc[nt][r] * as_v[nt];
      pd += acc[nt][r] * ad_v[nt];
    }
    #pragma unroll
    for (int msk = 1; msk < 16; msk <<= 1) {
      ps += __shfl_xor(ps, msk);
      pd += __shfl_xor(pd, msk);
    }
    if (gm < M) {
      __half2 h0 = __floats2half2_rn(acc[0][r], acc[1][r]);
      __half2 h1 = __floats2half2_rn(acc[2][r], acc[3][r]);
      __half2 h2 = __floats2half2_rn(acc[4][r], acc[5][r]);
      __half2 h3 = __floats2half2_rn(acc[6][r], acc[7][r]);
      uint4 u;
      u.x = *(unsigned*)&h0; u.y = *(unsigned*)&h1;
      u.z = *(unsigned*)&h2; u.w = *(unsigned*)&h3;
      *(uint4*)&H16[(size_t)gm * FH + col * 8] = u;
      if (col == 0) { a_s[gm] = ps; a_d[gm] = pd; }
    }
  }
}

// ---------------- GAT aggregation: wave/node, 4 slots x 16 lanes, unroll x2 -----
// OUTP=1: write packed-A16 fp16 (feeds next GEMM).
// OUTP=0: fused node head — no feature output at all; writes bout + pbuf.
template<int OUTP>
__global__ __launch_bounds__(256) void agg_kernel(
    const __half* __restrict__ H16, const int* __restrict__ rowptr,
    const unsigned int* __restrict__ pack,
    const float* __restrict__ a_s, const float* __restrict__ a_d,
    const float* __restrict__ cv, int cidx,
    const float* __restrict__ bias,
    __half* __restrict__ HoutP,
    const float* __restrict__ Wb, const float* __restrict__ bb,
    const float* __restrict__ Ww, const float* __restrict__ mask,
    float* __restrict__ bout, float* __restrict__ pbuf, int N) {
  const int node = (blockIdx.x * 256 + threadIdx.x) >> 6;
  const int lane = threadIdx.x & 63;
  const int slot = lane >> 4, sl = lane & 15;
  if (node >= N) return;
  const _Float16* __restrict__ Hh = (const _Float16*)H16;
  const float c   = cv[cidx];
  const float adn = a_d[node];
  const int beg = rowptr[node], end = rowptr[node + 1];

  float acc[8] = {0.f, 0.f, 0.f, 0.f, 0.f, 0.f, 0.f, 0.f};
  float accB[8] = {0.f, 0.f, 0.f, 0.f, 0.f, 0.f, 0.f, 0.f};
  float den = 0.f, ea_tot = 0.f, denB = 0.f, eaB = 0.f;

  int p = beg + slot;
  for (; p + 4 < end; p += 8) {              // 2 edges per slot in flight
    unsigned w0 = pack[p], w1 = pack[p + 4];
    int s0 = w0 >> 16, s1 = w1 >> 16;
    float e0 = __half2float(__ushort_as_half((unsigned short)(w0 & 0xffff)));
    float e1 = __half2float(__ushort_as_half((unsigned short)(w1 & 0xffff)));
    float as0 = a_s[s0], as1 = a_s[s1];
    f16x8 h0 = *(const f16x8*)(Hh + (size_t)s0 * FH + sl * 8);
    f16x8 h1 = *(const f16x8*)(Hh + (size_t)s1 * FH + sl * 8);
    float al0 = as0 + adn + c * e0;
    float al1 = as1 + adn + c * e1;
    al0 = fmaxf(al0, NEG_SLOPE * al0);
    al1 = fmaxf(al1, NEG_SLOPE * al1);
    float ex0 = __expf(al0), ex1 = __expf(al1);
    ea_tot += e0; eaB += e1;
    den += ex0; denB += ex1;
    #pragma unroll
    for (int j = 0; j < 8; j++) {
      acc[j]  += ex0 * (float)h0[j];
      accB[j] += ex1 * (float)h1[j];
    }
  }
  for (; p < end; p += 4) {
    unsigned w0 = pack[p];
    int s0 = w0 >> 16;
    float e0 = __half2float(__ushort_as_half((unsigned short)(w0 & 0xffff)));
    float al = a_s[s0] + adn + c * e0;
    al = fmaxf(al, NEG_SLOPE * al);
    float ex = __expf(al);
    f16x8 h = *(const f16x8*)(Hh + (size_t)s0 * FH + sl * 8);
    ea_tot += e0;
    den += ex;
    #pragma unroll
    for (int j = 0; j < 8; j++) acc[j] += ex * (float)h[j];
  }
  den += denB; ea_tot += eaB;
  #pragma unroll
  for (int j = 0; j < 8; j++) acc[j] += accB[j];
  // cross-slot reduce (slots differ in lane bits 4,5)
  ea_tot += __shfl_xor(ea_tot, 16); ea_tot += __shfl_xor(ea_tot, 32);
  den    += __shfl_xor(den,    16); den    += __shfl_xor(den,    32);
  #pragma unroll
  for (int j = 0; j < 8; j++) {
    acc[j] += __shfl_xor(acc[j], 16);
    acc[j] += __shfl_xor(acc[j], 32);
  }
  { // self loop, ea = mean of incoming edge attrs (0 if none)
    int dg = end - beg;
    float eal = ea_tot / fmaxf((float)dg, 1.f);
    float al = a_s[node] + adn + c * eal;
    al = fmaxf(al, NEG_SLOPE * al);
    float ex = __expf(al);
    f16x8 h = *(const f16x8*)(Hh + (size_t)node * FH + sl * 8);
    den += ex;
    #pragma unroll
    for (int j = 0; j < 8; j++) acc[j] += ex * (float)h[j];
  }
  if (slot == 0) {
    float inv = 1.f / den;
    float v[8];
    #pragma unroll
    for (int j = 0; j < 8; j++)
      v[j] = fmaxf(acc[j] * inv + bias[j * 16 + sl], 0.f);   // permuted bias gather
    if (OUTP) {
      // packed-A16 write: tile mg=node>>4, octet q=sl, row r=node&15
      f16x8 o;
      #pragma unroll
      for (int j = 0; j < 8; j++) o[j] = (_Float16)v[j];
      int mg = node >> 4, r = node & 15;
      *(f16x8*)((_Float16*)HoutP + (((size_t)mg * 16 + sl) * 16 + r) * 8) = o;
    } else {
      // fused node head: sb = v . Wb, sw = v . Ww over this slot's 8 features
      float sb = 0.f, sw = 0.f;
      #pragma unroll
      for (int j = 0; j < 8; j++) {
        int f = j * 16 + sl;                 // feature of permuted position sl*8+j
        sb += v[j] * Wb[f];
        sw += v[j] * Ww[f];
      }
      #pragma unroll
      for (int m = 1; m < 16; m <<= 1) {     // reduce across slot-0's 16 lanes
        sb += __shfl_xor(sb, m);
        sw += __shfl_xor(sw, m);
      }
      if (sl == 0) {
        bout[node] = (sb + bb[0]) * mask[node];
        pbuf[node] = sw;
      }
    }
  }
}

// ---------------- edge head: w = 0.5*(p[src]+p[dst]) + bw, x4 vectorized ---------
__global__ void edge_head_kernel(const int* __restrict__ ei, const float* __restrict__ p,
                                 const float* __restrict__ bw, float* __restrict__ w, int E) {
  int base = (blockIdx.x * 256 + threadIdx.x) * 4;
  if (base >= E) return;
  float b = bw[0];
  if (base + 4 <= E) {
    int4 s = *(const int4*)&ei[base];
    int4 d = *(const int4*)&ei[E + base];
    float4 o;
    o.x = 0.5f * (p[s.x] + p[d.x]) + b;
    o.y = 0.5f * (p[s.y] + p[d.y]) + b;
    o.z = 0.5f * (p[s.z] + p[d.z]) + b;
    o.w = 0.5f * (p[s.w] + p[d.w]) + b;
    *(float4*)&w[base] = o;
  } else {
    for (int e = base; e < E; e++)
      w[e] = 0.5f * (p[ei[e]] + p[ei[E + e]]) + b;
  }
}

extern "C" void kernel_launch(void* const* d_in, const int* in_sizes, int n_in,
                              void* d_out, int out_size, void* d_ws, size_t ws_size,
                              hipStream_t stream) {
  (void)n_in; (void)out_size; (void)ws_size;
  const float* x    = (const float*)d_in[0];
  const int*   ei   = (const int*)  d_in[1];
  const float* ea   = (const float*)d_in[2];
  const float* mask = (const float*)d_in[3];
  const float* W1   = (const float*)d_in[4];
  const float* b1   = (const float*)d_in[5];
  const float* as1  = (const float*)d_in[6];
  const float* ad1  = (const float*)d_in[7];
  const float* We1  = (const float*)d_in[8];
  const float* ae1  = (const float*)d_in[9];
  const float* W2   = (const float*)d_in[10];
  const float* b2   = (const float*)d_in[11];
  const float* as2  = (const float*)d_in[12];
  const float* ad2  = (const float*)d_in[13];
  const float* We2  = (const float*)d_in[14];
  const float* ae2  = (const float*)d_in[15];
  const float* Wb   = (const float*)d_in[16];
  const float* bb   = (const float*)d_in[17];
  const float* Ww   = (const float*)d_in[18];
  const float* bw   = (const float*)d_in[19];

  const int N  = in_sizes[3];          // 50000 (divisible by 16)
  const int E  = in_sizes[1] / 2;      // 1600000
  const int K1 = in_sizes[0] / N;      // 503
  const int K1p = (K1 + GBK - 1) & ~(GBK - 1);   // 512
  const int NBr = (E + HT * TB - 1) / (HT * TB); // 196 CSR-build blocks
  const int NT  = N / 16;                        // 3125 row tiles

  // ---- workspace carve-up (256B aligned) ----
  char* ws = (char*)d_ws;
  size_t off0 = 0;
  auto alloc = [&](size_t bytes) -> char* {
    char* q = ws + off0;
    off0 = (off0 + bytes + 255) & ~(size_t)255;
    return q;
  };
  int*   cnt    = (int*)  alloc((size_t)N * 4);
  int*   rowptr = (int*)  alloc((size_t)(N + 1) * 4);
  int*   bsum   = (int*)  alloc(1024 * 4);
  // Union region: hist/off (19.6 MB, dies after place) -> XA16 (51.2 MB, dies
  // after gemm1) -> HB16 (12.8 MB, written by agg1 after gemm1, dies after gemm2)
  size_t uszA = (size_t)NBr * N * 2;
  size_t uszB = (size_t)NT * (K1p / 8) * 256;    // 51.2 MB
  char*  uni  = alloc(uszA > uszB ? uszA : uszB);
  unsigned short* hist = (unsigned short*)uni;
  __half* XA16 = (__half*)uni;
  __half* HB16 = (__half*)uni;
  unsigned int* pack = (unsigned int*)alloc((size_t)E * 4);
  float* a_s    = (float*)alloc((size_t)N * 4);
  float* a_d    = (float*)alloc((size_t)N * 4);
  __half* H16   = (__half*)alloc((size_t)N * FH * 2);  // fp16 GEMM out (permuted cols)
  float* pbuf   = (float*)alloc((size_t)N * 4);
  float* cv     = (float*)alloc(8);
  __half* W1t   = (__half*)alloc((size_t)FH * K1p * 2);
  __half* W2t   = (__half*)alloc((size_t)FH * FH * 2);

  float* w_out = (float*)d_out;        // [E]
  float* b_out = (float*)d_out + E;    // [N]

  const int nb  = (N + 255) / 256;
  const int gb  = (N + GBM - 1) / GBM;
  const int ab  = (N + 3) / 4;                    // agg: 4 nodes/block
  const int eb4 = (E + 1023) / 1024;              // edge head: 4 edges/thread

  // topology precompute: ZERO global atomics, 8 edges/thread batched MLP
  hist_kernel   <<<NBr, HT, 0, stream>>>(ei, hist, E, N);
  colscan_kernel<<<nb, 256, 0, stream>>>(hist, cnt, N, NBr);
  scan_blocksum <<<nb, 256, 0, stream>>>(cnt, bsum, N);
  scan_bsum     <<<1, 1024, 0, stream>>>(bsum, nb, rowptr, N);
  scan_final    <<<nb, 256, 0, stream>>>(cnt, bsum, rowptr, N);
  place_kernel  <<<NBr, HT, 0, stream>>>(ei, ea, rowptr, hist, pack, E, N);
  cvec_kernel   <<<1, 64, 0, stream>>>(We1, ae1, We2, ae2, cv);
  wcvt_kernel   <<<(128 * K1p + 255) / 256, 256, 0, stream>>>(W1, W1t, K1, K1p, 0);
  wcvt_kernel   <<<(128 * FH + 255) / 256, 256, 0, stream>>>(W2, W2t, FH, FH, 1);
  // X -> packed fp16 fragment tiles (after place: reuses hist region)
  xpack_kernel  <<<NT, 256, 0, stream>>>(x, XA16, K1, K1p);

  // layer 1 (packed-A GEMM, fused a_s/a_d; H16 permuted); agg1 emits packed A16
  mfma_gemm_kernel<<<gb, 256, 0, stream>>>(XA16, W1t, as1, ad1, H16, a_s, a_d, N, K1p);
  agg_kernel<1><<<ab, 256, 0, stream>>>(H16, rowptr, pack, a_s, a_d, cv, 0, b1,
                                        HB16, nullptr, nullptr, nullptr, nullptr,
                                        nullptr, nullptr, N);
  // layer 2 (packed-A input from agg1; W2t k-permuted to match positions)
  mfma_gemm_kernel<<<gb, 256, 0, stream>>>(HB16, W2t, as2, ad2, H16, a_s, a_d, N, FH);
  // agg2 with fused node head: writes b_out and pbuf directly, no feature output
  agg_kernel<0><<<ab, 256, 0, stream>>>(H16, rowptr, pack, a_s, a_d, cv, 1, b2,
                                        nullptr, Wb, bb, Ww, mask, b_out, pbuf, N);
  edge_head_kernel<<<eb4, 256, 0, stream>>>(ei, pbuf, bw, w_out, E);
}